// Round 5
// baseline (163.555 us; speedup 1.0000x reference)
//
#include <hip/hip_runtime.h>

#define BATCH 32
#define SEQL 4096
#define NCH 128
#define CHUNK 64
#define WARMUP 192
#define STAGE (WARMUP + CHUNK)   // 256 staged steps max
#define EM 0.9f
#define EM4 0.6561f              // 0.9^4
#define C0 0.0729f               // 0.1 * 0.9^3
#define C1 0.081f                // 0.1 * 0.9^2
#define C2 0.09f                 // 0.1 * 0.9^1
#define C3 0.1f                  // 0.1 * 0.9^0

// One block = one (batch, 64-step output chunk); 128 threads = 1 channel each.
// EMA memory is geometric: 0.9^192 ~ 1.6e-9 => chunk-truncation error ~1e-3
// worst case through the 1e-6 clip (threshold 0.15). probs normalizer is
// identically 1 (EMA preserves one-hot row sums) => skip it.
// Warmup uses 4-step reassociated EMA: e[i+3] = 0.6561*e[i-1] + sum C_j x[i+j]
// -- side sum is independent of the carry, cutting the dependent-FMA chain
// 4x (192 -> 48) at equal VALU work.
__global__ __launch_bounds__(128) void mpe_kernel(
    const float* __restrict__ ts,
    const int* __restrict__ labels,
    const float* __restrict__ amounts,
    float* __restrict__ out)
{
    const int c = threadIdx.x;            // channel 0..127
    const int chunk = blockIdx.x;
    const int b = blockIdx.y;

    const int s = chunk * CHUNK;                      // first output index
    const int w = (s >= WARMUP) ? (s - WARMUP) : 0;   // first staged index
    const int total = s + CHUNK - w;                  // staged element count

    // packed per-step record: {amt, clipped_dt, label bits, pad}
    __shared__ float4 st[STAGE];

    const size_t rowbase = (size_t)b * SEQL;
    const float* tsr = ts + rowbase;

    for (int i = c; i < total; i += 128) {
        int gl = w + i;
        float d = 0.f;
        if (gl > 0) d = fminf(tsr[gl] - tsr[gl - 1], 100.f);
        st[i] = make_float4(amounts[rowbase + gl], d,
                            __int_as_float(labels[rowbase + gl]), 0.f);
    }
    __syncthreads();

    float p = 0.f, a = 0.f, dema = 0.f;
    int i = 0;
    const int out_begin = s - w;           // local index of first output step
    const int out_end = out_begin + CHUNK;

    if (w == 0) {
        // Exact init at gl=0: carry = x[0]
        float4 v = st[0];
        bool mine = (c == __float_as_int(v.z));
        p = mine ? 1.f : 0.f;
        a = mine ? v.x : 0.f;
        dema = 0.f;                        // first delta is 0 by construction
        if (s == 0) {
            size_t base0 = rowbase * (size_t)257;
            out[base0 + 1 + c] = p;
            out[base0 + 1 + NCH + c] = __fdividef(a, fmaxf(p, 1e-6f));
            if (c == 0) out[base0] = dema;
        }
        i = 1;
    }

    // Peel warmup to 4-step alignment. Guard: peel ONLY inside the warmup
    // region (round-4 bug: for s==0, out_begin==0 < i==1 and the unguarded
    // (out_begin-i)&3 peeled 3 OUTPUT steps without writing them).
    int rem = (out_begin > i) ? ((out_begin - i) & 3) : 0;
    for (int k = 0; k < rem; ++k, ++i) {
        float4 v = st[i];
        bool mine = (c == __float_as_int(v.z));
        p = fmaf(p, EM, mine ? 0.1f : 0.f);
        a = fmaf(a, EM, mine ? 0.1f * v.x : 0.f);
        dema = fmaf(dema, EM, 0.1f * v.y);
    }

    // Grouped warmup: 1 chain-FMA per 4 steps; side terms off the chain.
    for (; i < out_begin; i += 4) {
        float4 v0 = st[i], v1 = st[i + 1], v2 = st[i + 2], v3 = st[i + 3];
        bool m0 = (c == __float_as_int(v0.z));
        bool m1 = (c == __float_as_int(v1.z));
        bool m2 = (c == __float_as_int(v2.z));
        bool m3 = (c == __float_as_int(v3.z));
        float tp = (m0 ? C0 : 0.f) + (m1 ? C1 : 0.f)
                 + (m2 ? C2 : 0.f) + (m3 ? C3 : 0.f);
        float ta = (m0 ? C0 * v0.x : 0.f) + (m1 ? C1 * v1.x : 0.f)
                 + (m2 ? C2 * v2.x : 0.f) + (m3 ? C3 * v3.x : 0.f);
        float td = fmaf(C0, v0.y, fmaf(C1, v1.y, fmaf(C2, v2.y, C3 * v3.y)));
        p = fmaf(p, EM4, tp);
        a = fmaf(a, EM4, ta);
        dema = fmaf(dema, EM4, td);
    }

    // Output phase: evolve + write 257 floats/step; pointer-increment addressing.
    float* po = out + (rowbase + w + i) * (size_t)257;
    for (; i < out_end; ++i) {
        float4 v = st[i];
        bool mine = (c == __float_as_int(v.z));
        p = fmaf(p, EM, mine ? 0.1f : 0.f);
        a = fmaf(a, EM, mine ? 0.1f * v.x : 0.f);
        dema = fmaf(dema, EM, 0.1f * v.y);
        po[1 + c] = p;
        po[1 + NCH + c] = __fdividef(a, fmaxf(p, 1e-6f));
        if (c == 0) po[0] = dema;
        po += 257;
    }
}

extern "C" void kernel_launch(void* const* d_in, const int* in_sizes, int n_in,
                              void* d_out, int out_size, void* d_ws, size_t ws_size,
                              hipStream_t stream) {
    const float* ts      = (const float*)d_in[0];
    const int*   labels  = (const int*)d_in[1];
    const float* amounts = (const float*)d_in[2];
    float* out = (float*)d_out;

    dim3 grid(SEQL / CHUNK, BATCH);   // 64 x 32 = 2048 blocks
    mpe_kernel<<<grid, 128, 0, stream>>>(ts, labels, amounts, out);
}

// Round 6
// 151.812 us; speedup vs baseline: 1.0773x; 1.0773x over previous
//
#include <hip/hip_runtime.h>

#define BATCH 32
#define SEQL 4096
#define NCH 128
#define CHUNK 64
#define WARMUP 192
#define STAGE (WARMUP + CHUNK)   // 256 staged steps max
#define GSTEP 16                 // output steps buffered per LDS flush
#define ROWF 257                 // floats per output step
#define EM 0.9f
#define EM4 0.6561f              // 0.9^4
#define C0 0.0729f               // 0.1 * 0.9^3
#define C1 0.081f                // 0.1 * 0.9^2
#define C2 0.09f                 // 0.1 * 0.9^1
#define C3 0.1f                  // 0.1 * 0.9^0

// One block = one (batch, 64-step output chunk); 128 threads = 1 channel each.
// EMA memory is geometric: 0.9^192 ~ 1.6e-9 => chunk truncation error ~1e-3
// worst case through the 1e-6 clip (threshold 0.15). probs normalizer == 1
// (EMA preserves one-hot row sums) => skip it.
//
// Store path: output row stride is 1028 B (== 4 mod 64), so direct per-step
// scalar stores hit ~5 partial 64B sectors per step -> L2/HBM read-modify-
// write, measured ~1.8 TB/s effective. Instead buffer GSTEP steps in LDS and
// flush 16448 B contiguous per group with aligned dwordx4 (group base byte
// offset = (b*4096 + s + 16g)*1028 which is ≡ 0 mod 64).
__global__ __launch_bounds__(128) void mpe_kernel(
    const float* __restrict__ ts,
    const int* __restrict__ labels,
    const float* __restrict__ amounts,
    float* __restrict__ out)
{
    const int c = threadIdx.x;            // channel 0..127
    const int chunk = blockIdx.x;
    const int b = blockIdx.y;

    const int s = chunk * CHUNK;                      // first output index
    const int w = (s >= WARMUP) ? (s - WARMUP) : 0;   // first staged index
    const int total = s + CHUNK - w;                  // staged element count

    __shared__ float2 s_ad[STAGE];                    // {amt, clipped dt}
    __shared__ int    s_lab[STAGE];
    __shared__ __align__(16) float obuf[GSTEP * ROWF]; // 16448 B

    const size_t rowbase = (size_t)b * SEQL;
    const float* tsr = ts + rowbase;

    for (int i = c; i < total; i += 128) {
        int gl = w + i;
        float d = (gl > 0) ? fminf(tsr[gl] - tsr[gl - 1], 100.f) : 0.f;
        s_ad[i] = make_float2(amounts[rowbase + gl], d);
        s_lab[i] = labels[rowbase + gl];
    }
    __syncthreads();

    float p = 0.f, a = 0.f, dema = 0.f;
    int i = 0;
    const int out_begin = s - w;           // local index of first output step

    if (w == 0) {
        // Exact init at gl=0: carry = x[0]
        bool mine = (c == s_lab[0]);
        p = mine ? 1.f : 0.f;
        a = mine ? s_ad[0].x : 0.f;
        dema = 0.f;                        // first delta is 0 by construction
        i = 1;
    }

    // Peel warmup to 4-step alignment; guard: peel ONLY inside warmup
    // (for s==0, out_begin==0 < i==1 must not peel output steps).
    int rem = (out_begin > i) ? ((out_begin - i) & 3) : 0;
    for (int k = 0; k < rem; ++k, ++i) {
        bool mine = (c == s_lab[i]);
        float2 ad = s_ad[i];
        p = fmaf(p, EM, mine ? 0.1f : 0.f);
        a = fmaf(a, EM, mine ? 0.1f * ad.x : 0.f);
        dema = fmaf(dema, EM, 0.1f * ad.y);
    }

    // Grouped warmup: 1 chain-FMA per 4 steps; side terms off the chain.
    for (; i < out_begin; i += 4) {
        int l0 = s_lab[i], l1 = s_lab[i+1], l2 = s_lab[i+2], l3 = s_lab[i+3];
        float2 a0 = s_ad[i], a1 = s_ad[i+1], a2 = s_ad[i+2], a3 = s_ad[i+3];
        bool m0 = (c == l0), m1 = (c == l1), m2 = (c == l2), m3 = (c == l3);
        float tp = (m0 ? C0 : 0.f) + (m1 ? C1 : 0.f)
                 + (m2 ? C2 : 0.f) + (m3 ? C3 : 0.f);
        float ta = (m0 ? C0 * a0.x : 0.f) + (m1 ? C1 * a1.x : 0.f)
                 + (m2 ? C2 * a2.x : 0.f) + (m3 ? C3 * a3.x : 0.f);
        float td = fmaf(C0, a0.y, fmaf(C1, a1.y, fmaf(C2, a2.y, C3 * a3.y)));
        p = fmaf(p, EM4, tp);
        a = fmaf(a, EM4, ta);
        dema = fmaf(dema, EM4, td);
    }

    // Output phase: GSTEP-step groups {evolve into LDS, sync, dwordx4 flush}.
    for (int g = 0; g < CHUNK / GSTEP; ++g) {
        const int gstart = out_begin + g * GSTEP;
        const int lend = gstart + GSTEP;

        if (s == 0 && g == 0) {
            // row 0 of the first group is the exact-init state (gl = 0)
            obuf[1 + c] = p;
            obuf[1 + NCH + c] = __fdividef(a, fmaxf(p, 1e-6f));
            if (c == 0) obuf[0] = 0.f;
        }

        #pragma unroll 4
        for (; i < lend; ++i) {
            bool mine = (c == s_lab[i]);
            float2 ad = s_ad[i];
            p = fmaf(p, EM, mine ? 0.1f : 0.f);
            a = fmaf(a, EM, mine ? 0.1f * ad.x : 0.f);
            dema = fmaf(dema, EM, 0.1f * ad.y);
            const int ro = (i - gstart) * ROWF;
            obuf[ro + 1 + c] = p;
            obuf[ro + 1 + NCH + c] = __fdividef(a, fmaxf(p, 1e-6f));
            if (c == 0) obuf[ro] = dema;
        }
        __syncthreads();

        // Flush 16448 B = 1028 dwordx4, base ≡ 0 mod 64 B.
        float4* gout = (float4*)(out + (rowbase + s + g * GSTEP) * (size_t)ROWF);
        const float4* ob4 = (const float4*)obuf;
        for (int k = c; k < GSTEP * ROWF / 4; k += 128)
            gout[k] = ob4[k];
        __syncthreads();
    }
}

extern "C" void kernel_launch(void* const* d_in, const int* in_sizes, int n_in,
                              void* d_out, int out_size, void* d_ws, size_t ws_size,
                              hipStream_t stream) {
    const float* ts      = (const float*)d_in[0];
    const int*   labels  = (const int*)d_in[1];
    const float* amounts = (const float*)d_in[2];
    float* out = (float*)d_out;

    dim3 grid(SEQL / CHUNK, BATCH);   // 64 x 32 = 2048 blocks
    mpe_kernel<<<grid, 128, 0, stream>>>(ts, labels, amounts, out);
}